// Round 1
// baseline (710.706 us; speedup 1.0000x reference)
//
#include <hip/hip_runtime.h>
#include <cstddef>

// Problem constants
#define Bc 4
#define Nc 1024
#define Cc 768
#define Hc 12
#define Dc 64
#define QKV_ELEMS ((size_t)Bc * Nc * Cc)   // 3145728

// ---------------------------------------------------------------------------
// K1/K5: out = A[4096x768] @ W[768x768] + bias
// MODE 0: out row-major [4096,768]; MODE 1: head layout [B,H,N,D]
// 64x64 block tile, BK=16, 256 threads, 4x4 per thread. LDS stride 68 (pad).
// ---------------------------------------------------------------------------
template <int MODE>
__global__ __launch_bounds__(256) void gemm768_kernel(
    const float* __restrict__ A, const float* __restrict__ W,
    const float* __restrict__ bias, float* __restrict__ out)
{
    __shared__ float As[16][68];  // [k][m]
    __shared__ float Bs[16][68];  // [k][n]
    const int tid = threadIdx.x;
    const int tx = tid & 15, ty = tid >> 4;
    const int m0 = blockIdx.y * 64, n0 = blockIdx.x * 64;

    float acc[4][4] = {};

    for (int kk = 0; kk < 768; kk += 16) {
        {   // A tile: 64 rows x 16 k, transposed store
            const int r  = tid >> 2;
            const int c4 = (tid & 3) << 2;
            const float4 a = *(const float4*)&A[(size_t)(m0 + r) * 768 + kk + c4];
            As[c4 + 0][r] = a.x; As[c4 + 1][r] = a.y;
            As[c4 + 2][r] = a.z; As[c4 + 3][r] = a.w;
        }
        {   // W tile: 16 k rows x 64 cols
            const int r  = tid >> 4;
            const int c4 = (tid & 15) << 2;
            *(float4*)&Bs[r][c4] = *(const float4*)&W[(size_t)(kk + r) * 768 + n0 + c4];
        }
        __syncthreads();
        #pragma unroll
        for (int k = 0; k < 16; ++k) {
            const float4 a = *(const float4*)&As[k][ty * 4];
            const float4 b = *(const float4*)&Bs[k][tx * 4];
            const float av[4] = {a.x, a.y, a.z, a.w};
            const float bv[4] = {b.x, b.y, b.z, b.w};
            #pragma unroll
            for (int i = 0; i < 4; ++i)
                #pragma unroll
                for (int j = 0; j < 4; ++j)
                    acc[i][j] = fmaf(av[i], bv[j], acc[i][j]);
        }
        __syncthreads();
    }

    const int col0 = n0 + tx * 4;
    #pragma unroll
    for (int i = 0; i < 4; ++i) {
        const int m = m0 + ty * 4 + i;
        float4 r;
        r.x = acc[i][0] + bias[col0 + 0];
        r.y = acc[i][1] + bias[col0 + 1];
        r.z = acc[i][2] + bias[col0 + 2];
        r.w = acc[i][3] + bias[col0 + 3];
        if (MODE == 0) {
            *(float4*)&out[(size_t)m * 768 + col0] = r;
        } else {
            const int b = m >> 10, nn = m & 1023;
            const int h = col0 >> 6, d = col0 & 63;
            *(float4*)&out[(((size_t)(b * Hc + h) * Nc + nn) << 6) + d] = r;
        }
    }
}

// ---------------------------------------------------------------------------
// K2: pre-softmax scores = q.k^T * scale + spatialMLP(dist)  -> attn region
// grid (j-tiles=32, i-tiles=32, b*h=48), 256 threads, 32x32 scores per block
// ---------------------------------------------------------------------------
__global__ __launch_bounds__(256) void scores_kernel(
    const float* __restrict__ q, const float* __restrict__ k,
    const float* __restrict__ coords,
    const float* __restrict__ Wd1, const float* __restrict__ bd1,
    const float* __restrict__ Wd2, const float* __restrict__ bd2,
    float* __restrict__ attn)
{
    constexpr int ST = 68;
    __shared__ float Qs[32 * ST], Ks[32 * ST];
    __shared__ float ci[32][2], cj[32][2];
    __shared__ float w1[16], b1[16], w2[192];

    const int tid = threadIdx.x;
    const int bh = blockIdx.z;
    const int b = bh / Hc, h = bh % Hc;
    const int i0 = blockIdx.y * 32, j0 = blockIdx.x * 32;

    const float* qbase = q + ((size_t)bh * Nc + i0) * Dc;
    const float* kbase = k + ((size_t)bh * Nc + j0) * Dc;

    #pragma unroll
    for (int t = tid; t < 512; t += 256) {
        const int r = t >> 4, c4 = (t & 15) << 2;
        *(float4*)&Qs[r * ST + c4] = *(const float4*)&qbase[t << 2];
        *(float4*)&Ks[r * ST + c4] = *(const float4*)&kbase[t << 2];
    }
    if (tid < 192) {
        w2[tid] = Wd2[tid];
    } else if (tid < 224) {
        const int t = tid - 192;
        ci[t][0] = coords[((size_t)b * Nc + i0 + t) * 2 + 0];
        ci[t][1] = coords[((size_t)b * Nc + i0 + t) * 2 + 1];
    } else {
        const int t = tid - 224;
        cj[t][0] = coords[((size_t)b * Nc + j0 + t) * 2 + 0];
        cj[t][1] = coords[((size_t)b * Nc + j0 + t) * 2 + 1];
    }
    if (tid >= 64 && tid < 80) {
        w1[tid - 64] = Wd1[tid - 64];
        b1[tid - 64] = bd1[tid - 64];
    }
    __syncthreads();

    const int i  = tid >> 3;          // 0..31
    const int jb = (tid & 7) << 2;    // 0,4,...,28

    float dotv[4] = {};
    #pragma unroll
    for (int d = 0; d < 64; d += 4) {
        const float4 a = *(const float4*)&Qs[i * ST + d];
        #pragma unroll
        for (int jj = 0; jj < 4; ++jj) {
            const float4 kv = *(const float4*)&Ks[(jb + jj) * ST + d];
            dotv[jj] += a.x * kv.x + a.y * kv.y + a.z * kv.z + a.w * kv.w;
        }
    }

    const float bd2h = bd2[h];
    const float cix = ci[i][0], ciy = ci[i][1];
    float res[4];
    #pragma unroll
    for (int jj = 0; jj < 4; ++jj) {
        const float dx = cix - cj[jb + jj][0];
        const float dy = ciy - cj[jb + jj][1];
        const float dist = sqrtf(dx * dx + dy * dy + 1e-6f);
        float s = bd2h;
        #pragma unroll
        for (int t = 0; t < 16; ++t) {
            const float hb = fmaxf(fmaf(dist, w1[t], b1[t]), 0.0f);
            s = fmaf(hb, w2[t * 12 + h], s);
        }
        res[jj] = dotv[jj] * 0.125f + s;
    }
    float4 r4 = make_float4(res[0], res[1], res[2], res[3]);
    *(float4*)&attn[((size_t)bh * Nc + i0 + i) * Nc + j0 + jb] = r4;
}

// ---------------------------------------------------------------------------
// K3: in-place row softmax over last dim (1024). One block per row.
// ---------------------------------------------------------------------------
__global__ __launch_bounds__(256) void softmax_kernel(float* __restrict__ attn)
{
    const size_t row = blockIdx.x;
    float* p = attn + row * Nc;
    const int tid = threadIdx.x;

    float4 x = ((const float4*)p)[tid];
    float m = fmaxf(fmaxf(x.x, x.y), fmaxf(x.z, x.w));
    #pragma unroll
    for (int off = 32; off > 0; off >>= 1) m = fmaxf(m, __shfl_xor(m, off));

    __shared__ float smax[4], ssum[4];
    if ((tid & 63) == 0) smax[tid >> 6] = m;
    __syncthreads();
    m = fmaxf(fmaxf(smax[0], smax[1]), fmaxf(smax[2], smax[3]));

    float4 e;
    e.x = __expf(x.x - m); e.y = __expf(x.y - m);
    e.z = __expf(x.z - m); e.w = __expf(x.w - m);
    float s = e.x + e.y + e.z + e.w;
    #pragma unroll
    for (int off = 32; off > 0; off >>= 1) s += __shfl_xor(s, off);
    if ((tid & 63) == 0) ssum[tid >> 6] = s;
    __syncthreads();
    const float inv = 1.0f / (ssum[0] + ssum[1] + ssum[2] + ssum[3]);

    e.x *= inv; e.y *= inv; e.z *= inv; e.w *= inv;
    ((float4*)p)[tid] = e;
}

// ---------------------------------------------------------------------------
// K4: heads[b, i, h*64+d] = sum_j attn[b,h,i,j] * v[b,h,j,d]
// grid (i-tiles=16, bh=48); 64x64 output tile; 256 threads, 4x4 per thread.
// ---------------------------------------------------------------------------
__global__ __launch_bounds__(256) void pv_kernel(
    const float* __restrict__ attn, const float* __restrict__ v,
    float* __restrict__ heads)
{
    constexpr int AST = 68;
    __shared__ float As[64 * AST];   // attn tile [i][j], padded
    __shared__ float Vs[64 * 64];    // v tile [j][d]

    const int tid = threadIdx.x;
    const int bh = blockIdx.y;
    const int b = bh / Hc, h = bh % Hc;
    const int i0 = blockIdx.x * 64;
    const int tx = tid & 15, ty = tid >> 4;

    float acc[4][4] = {};

    for (int kk = 0; kk < Nc; kk += 64) {
        const float4* vsrc = (const float4*)(v + ((size_t)bh * Nc + kk) * Dc);
        #pragma unroll
        for (int t = tid; t < 1024; t += 256) {
            const int r = t >> 4, c4 = (t & 15) << 2;
            *(float4*)&As[r * AST + c4] =
                *(const float4*)&attn[((size_t)bh * Nc + i0 + r) * Nc + kk + c4];
            ((float4*)Vs)[t] = vsrc[t];
        }
        __syncthreads();
        #pragma unroll 8
        for (int jj = 0; jj < 64; ++jj) {
            const float4 bb = *(const float4*)&Vs[jj * 64 + tx * 4];
            #pragma unroll
            for (int ii = 0; ii < 4; ++ii) {
                const float a = As[(ty + (ii << 4)) * AST + jj];
                acc[ii][0] = fmaf(a, bb.x, acc[ii][0]);
                acc[ii][1] = fmaf(a, bb.y, acc[ii][1]);
                acc[ii][2] = fmaf(a, bb.z, acc[ii][2]);
                acc[ii][3] = fmaf(a, bb.w, acc[ii][3]);
            }
        }
        __syncthreads();
    }

    #pragma unroll
    for (int ii = 0; ii < 4; ++ii) {
        const int i = i0 + ty + (ii << 4);
        float4 r4 = make_float4(acc[ii][0], acc[ii][1], acc[ii][2], acc[ii][3]);
        *(float4*)&heads[((size_t)b * Nc + i) * Cc + h * Dc + tx * 4] = r4;
    }
}

// ---------------------------------------------------------------------------
extern "C" void kernel_launch(void* const* d_in, const int* in_sizes, int n_in,
                              void* d_out, int out_size, void* d_ws, size_t ws_size,
                              hipStream_t stream)
{
    (void)in_sizes; (void)n_in; (void)out_size; (void)ws_size;

    const float* x      = (const float*)d_in[0];
    const float* coords = (const float*)d_in[1];
    const float* Wq = (const float*)d_in[2];  const float* bq = (const float*)d_in[3];
    const float* Wk = (const float*)d_in[4];  const float* bk = (const float*)d_in[5];
    const float* Wv = (const float*)d_in[6];  const float* bv = (const float*)d_in[7];
    const float* Wo = (const float*)d_in[8];  const float* bo = (const float*)d_in[9];
    const float* Wd1 = (const float*)d_in[10]; const float* bd1 = (const float*)d_in[11];
    const float* Wd2 = (const float*)d_in[12]; const float* bd2 = (const float*)d_in[13];

    float* out_main = (float*)d_out;            // [B,N,C]
    float* attn     = out_main + QKV_ELEMS;     // [B,H,N,N]

    float* q     = (float*)d_ws;                // [B,H,N,D]
    float* k     = q + QKV_ELEMS;
    float* v     = k + QKV_ELEMS;
    float* heads = v + QKV_ELEMS;               // [B,N,C]

    dim3 gGemm(12, 64);
    gemm768_kernel<1><<<gGemm, 256, 0, stream>>>(x, Wq, bq, q);
    gemm768_kernel<1><<<gGemm, 256, 0, stream>>>(x, Wk, bk, k);
    gemm768_kernel<1><<<gGemm, 256, 0, stream>>>(x, Wv, bv, v);

    dim3 gScores(32, 32, 48);
    scores_kernel<<<gScores, 256, 0, stream>>>(q, k, coords, Wd1, bd1, Wd2, bd2, attn);

    softmax_kernel<<<dim3(49152), 256, 0, stream>>>(attn);

    pv_kernel<<<dim3(16, 48), 256, 0, stream>>>(attn, v, heads);

    gemm768_kernel<0><<<gGemm, 256, 0, stream>>>(heads, Wo, bo, out_main);
}